// Round 8
// baseline (224.973 us; speedup 1.0000x reference)
//
#include <hip/hip_runtime.h>

#define D 300
#define HDIM 512
#define ROWS 64           // X rows per block
#define WPB 32            // words per block
#define KSTEPS 10
#define CHUNK_ELEMS 10240 // 10 ks * 32 cols * 32 k-elems

typedef __attribute__((ext_vector_type(4))) float f32x4;
typedef __attribute__((ext_vector_type(8))) short bf16x8;

__device__ inline unsigned short f2bf(float f) {
  unsigned int u = __float_as_uint(f);
  unsigned int r = (u + 0x7fffu + ((u >> 16) & 1u)) >> 16;
  return (unsigned short)r;
}

// Swizzled weight layout: wt[t][ks][c][kg][e], t=chunk (0..31 even=Q_g odd=K_g,
// g=t>>1; 32..47 = V_g), c=col-in-chunk (32), kg*8+e + ks*32 = k (zero-pad k>=300).
// A wave's per-ks B-fragment = contiguous 1KB: off = (cg*16+lrow)*32 + kgrp*8.
__global__ __launch_bounds__(256) void prep_weights(
    const float* __restrict__ Wq, const float* __restrict__ Wk,
    const float* __restrict__ Wv, unsigned short* __restrict__ wt) {
  int idx = blockIdx.x * 256 + threadIdx.x;
  if (idx >= 48 * CHUNK_ELEMS) return;
  int t = idx / CHUNK_ELEMS, r = idx - t * CHUNK_ELEMS;
  int ks = r >> 10, r2 = r & 1023;
  int c = r2 >> 5, r3 = r2 & 31;
  int k = ks * 32 + r3;
  const float* M;
  int col0;
  if (t < 32) { M = (t & 1) ? Wk : Wq; col0 = (t >> 1) * 32; }
  else        { M = Wv;                col0 = (t - 32) * 32; }
  float v = (k < D) ? M[k * HDIM + col0 + c] : 0.0f;
  wt[idx] = f2bf(v);
}

// Barrier-free hot loop: B-fragments straight from global (L1/L2-resident,
// coalesced via the swizzled layout). No LDS staging, no hot-loop barriers.
__global__ __launch_bounds__(256) void fused_attn(
    const float* __restrict__ charv, const float* __restrict__ wordv,
    const unsigned short* __restrict__ wt,
    const float* __restrict__ bk, const float* __restrict__ bq,
    const float* __restrict__ bv, float* __restrict__ out) {
  __shared__ float sS[256];   // [2 cg][32 w][4]
  __shared__ float sAt[128];  // [32 w][4]

  const int tid  = threadIdx.x;
  const int wid  = tid >> 6;
  const int lane = tid & 63;
  const int lrow = lane & 15;
  const int kgrp = lane >> 4;
  const int rg   = wid >> 1;   // 0..1 : rows rg*32 .. +32
  const int cg   = wid & 1;    // 0..1 : 16-col half of each 32-col chunk
  const int boff = (cg * 16 + lrow) * 32 + kgrp * 8;  // elems within a chunk-ks block

  // ---- X fragments: global f32 -> bf16 regs (one-time)
  bf16x8 a[2][KSTEPS];
#pragma unroll
  for (int rt = 0; rt < 2; ++rt) {
    int row = blockIdx.x * ROWS + rg * 32 + rt * 16 + lrow;
    const float* rp = ((row & 1) ? charv : wordv) + (row >> 1) * D;
#pragma unroll
    for (int ks = 0; ks < KSTEPS; ++ks) {
      int k0 = ks * 32 + kgrp * 8;
      float4 lo = {0.f, 0.f, 0.f, 0.f}, hi = {0.f, 0.f, 0.f, 0.f};
      if (k0 + 8 <= D) {
        lo = *(const float4*)(rp + k0);
        hi = *(const float4*)(rp + k0 + 4);
      } else if (k0 < D) {
        lo = *(const float4*)(rp + k0);
      }
      bf16x8 v;
      v[0] = (short)f2bf(lo.x); v[1] = (short)f2bf(lo.y);
      v[2] = (short)f2bf(lo.z); v[3] = (short)f2bf(lo.w);
      v[4] = (short)f2bf(hi.x); v[5] = (short)f2bf(hi.y);
      v[6] = (short)f2bf(hi.z); v[7] = (short)f2bf(hi.w);
      a[rt][ks] = v;
    }
  }

  float p[2][8];
#pragma unroll
  for (int rt = 0; rt < 2; ++rt)
#pragma unroll
    for (int t = 0; t < 8; ++t) p[rt][t] = 0.f;

  // ---- Phase A: 16 (Q_g, K_g) pairs; loads and MFMAs free-run, no barriers
  for (int g = 0; g < 16; ++g) {
    const bf16x8* cq = (const bf16x8*)(wt + (2 * g) * CHUNK_ELEMS + boff);
    const bf16x8* ck = (const bf16x8*)(wt + (2 * g + 1) * CHUNK_ELEMS + boff);
    float bqv = bq[g * 32 + cg * 16 + lrow];
    float bkv = bk[g * 32 + cg * 16 + lrow];
    f32x4 accQ[2], accK[2];
    accQ[0] = (f32x4){bqv, bqv, bqv, bqv};
    accQ[1] = accQ[0];
    accK[0] = (f32x4){bkv, bkv, bkv, bkv};
    accK[1] = accK[0];
#pragma unroll
    for (int ks = 0; ks < KSTEPS; ++ks) {
      bf16x8 bqf = cq[ks * 128];   // ks*1024 elems / 8 per bf16x8
      bf16x8 bkf = ck[ks * 128];
      accQ[0] = __builtin_amdgcn_mfma_f32_16x16x32_bf16(a[0][ks], bqf, accQ[0], 0, 0, 0);
      accQ[1] = __builtin_amdgcn_mfma_f32_16x16x32_bf16(a[1][ks], bqf, accQ[1], 0, 0, 0);
      accK[0] = __builtin_amdgcn_mfma_f32_16x16x32_bf16(a[0][ks], bkf, accK[0], 0, 0, 0);
      accK[1] = __builtin_amdgcn_mfma_f32_16x16x32_bf16(a[1][ks], bkf, accK[1], 0, 0, 0);
    }
    // lane-local score partials (same lane holds Q and K for same (word,col))
#pragma unroll
    for (int rt = 0; rt < 2; ++rt)
#pragma unroll
      for (int wl = 0; wl < 2; ++wl)
#pragma unroll
        for (int i = 0; i < 2; ++i)
#pragma unroll
          for (int j = 0; j < 2; ++j)
            p[rt][wl * 4 + i * 2 + j] += accQ[rt][wl * 2 + i] * accK[rt][wl * 2 + j];
  }

  // ---- reduce over 16 col-lanes, combine cg halves, softmax
#pragma unroll
  for (int rt = 0; rt < 2; ++rt)
#pragma unroll
    for (int t = 0; t < 8; ++t) {
      float v = p[rt][t];
      v += __shfl_xor(v, 1);
      v += __shfl_xor(v, 2);
      v += __shfl_xor(v, 4);
      v += __shfl_xor(v, 8);
      p[rt][t] = v;
    }
  if (lrow == 0) {
#pragma unroll
    for (int rt = 0; rt < 2; ++rt)
#pragma unroll
      for (int t = 0; t < 8; ++t) {
        int w = rg * 16 + rt * 8 + kgrp * 2 + (t >> 2);
        sS[cg * 128 + w * 4 + (t & 3)] = p[rt][t];
      }
  }
  __syncthreads();
  if (tid < 32) {
    const float sc = 0.044194173824159216f;  // 1/sqrt(512)
    float s[4];
#pragma unroll
    for (int t = 0; t < 4; ++t) s[t] = (sS[tid * 4 + t] + sS[128 + tid * 4 + t]) * sc;
#pragma unroll
    for (int i = 0; i < 2; ++i) {
      float m  = fmaxf(s[i * 2], s[i * 2 + 1]);
      float e0 = expf(s[i * 2] - m), e1 = expf(s[i * 2 + 1] - m);
      float inv = 1.0f / (e0 + e1);
      sAt[tid * 4 + i * 2]     = e0 * inv;
      sAt[tid * 4 + i * 2 + 1] = e1 * inv;
    }
  }
  __syncthreads();

  float at0[2][4], at1[2][4];
#pragma unroll
  for (int rt = 0; rt < 2; ++rt) {
    int wA = rg * 16 + rt * 8 + kgrp * 2;
#pragma unroll
    for (int t = 0; t < 4; ++t) {
      at0[rt][t] = sAt[wA * 4 + t];
      at1[rt][t] = sAt[(wA + 1) * 4 + t];
    }
  }

  // ---- Phase B: 16 V chunks + attention combine, still barrier-free
  for (int g = 0; g < 16; ++g) {
    const bf16x8* cv = (const bf16x8*)(wt + (32 + g) * CHUNK_ELEMS + boff);
    float bvv = bv[g * 32 + cg * 16 + lrow];
    f32x4 accV[2];
    accV[0] = (f32x4){bvv, bvv, bvv, bvv};
    accV[1] = accV[0];
#pragma unroll
    for (int ks = 0; ks < KSTEPS; ++ks) {
      bf16x8 b = cv[ks * 128];
      accV[0] = __builtin_amdgcn_mfma_f32_16x16x32_bf16(a[0][ks], b, accV[0], 0, 0, 0);
      accV[1] = __builtin_amdgcn_mfma_f32_16x16x32_bf16(a[1][ks], b, accV[1], 0, 0, 0);
    }
#pragma unroll
    for (int rt = 0; rt < 2; ++rt) {
      int gA = blockIdx.x * WPB + rg * 16 + rt * 8 + kgrp * 2;
      int h = g * 32 + cg * 16 + lrow;
      float* o = out + gA * 1024 + h;
      o[0]    = at0[rt][0] * accV[rt][0] + at0[rt][1] * accV[rt][1];
      o[512]  = at0[rt][2] * accV[rt][0] + at0[rt][3] * accV[rt][1];
      o[1024] = at1[rt][0] * accV[rt][2] + at1[rt][1] * accV[rt][3];
      o[1536] = at1[rt][2] * accV[rt][2] + at1[rt][3] * accV[rt][3];
    }
  }
}

extern "C" void kernel_launch(void* const* d_in, const int* in_sizes, int n_in,
                              void* d_out, int out_size, void* d_ws, size_t ws_size,
                              hipStream_t stream) {
  const float* charv = (const float*)d_in[0];
  const float* wordv = (const float*)d_in[1];
  const float* Wk = (const float*)d_in[2];
  const float* bk = (const float*)d_in[3];
  const float* Wq = (const float*)d_in[4];
  const float* bq = (const float*)d_in[5];
  const float* Wv = (const float*)d_in[6];
  const float* bv = (const float*)d_in[7];
  float* out = (float*)d_out;
  unsigned short* wt = (unsigned short*)d_ws;  // 48*10240*2 = 983,040 B

  prep_weights<<<(48 * CHUNK_ELEMS + 255) / 256, 256, 0, stream>>>(Wq, Wk, Wv, wt);
  fused_attn<<<65536 / ROWS, 256, 0, stream>>>(charv, wordv, wt, bk, bq, bv, out);
}

// Round 9
// 98.644 us; speedup vs baseline: 2.2807x; 2.2807x over previous
//
#include <hip/hip_runtime.h>

#define D 300
#define HDIM 512
#define ROWS 128          // X rows per block
#define WPB 64            // words per block
#define KSTEPS 10
#define NCH 24            // 16 [Q|K] chunks + 8 V chunks, 64 cols each
#define CH_BYTES 40960    // 64 cols * 320 k * 2 B
#define CH_ELEMS 20480
#define SEGW 5            // 1KB staging segments per wave per chunk (40/8)

typedef __attribute__((ext_vector_type(4))) float f32x4;
typedef __attribute__((ext_vector_type(8))) short bf16x8;

__device__ inline unsigned short f2bf(float f) {
  unsigned int u = __float_as_uint(f);
  unsigned int r = (u + 0x7fffu + ((u >> 16) & 1u)) >> 16;
  return (unsigned short)r;
}

__device__ inline void gload_lds16(const void* g, void* l) {
  __builtin_amdgcn_global_load_lds(
      (const __attribute__((address_space(1))) unsigned int*)g,
      (__attribute__((address_space(3))) unsigned int*)l, 16, 0, 0);
}

// Chunk-contiguous layout: wt[c][ks][col][kk] bf16 (c<16: cols 0-31 = Wq cols
// c*32.., cols 32-63 = Wk cols c*32..; c>=16: Wv cols (c-16)*64..). k>=300 zero.
// A wave's 16-col x 32-k fragment = contiguous 1KB -> conflict-free ds_read_b128
// and linear global_load_lds staging.
__global__ __launch_bounds__(512) void prep_weights(
    const float* __restrict__ Wq, const float* __restrict__ Wk,
    const float* __restrict__ Wv, unsigned short* __restrict__ wt) {
  int idx = blockIdx.x * 512 + threadIdx.x;   // grid covers exactly NCH*CH_ELEMS
  int c = idx / CH_ELEMS, r = idx - c * CH_ELEMS;
  int ks = r >> 11, r2 = r & 2047;
  int col = r2 >> 5, kk = r2 & 31;
  int k = ks * 32 + kk;
  const float* M; int gcol;
  if (c < 16) {
    if (col < 32) { M = Wq; gcol = c * 32 + col; }
    else          { M = Wk; gcol = c * 32 + col - 32; }
  } else { M = Wv; gcol = (c - 16) * 64 + col; }
  float v = (k < D) ? M[k * HDIM + gcol] : 0.0f;
  wt[idx] = f2bf(v);
}

// Triple-buffered counted-vmcnt pipeline: one s_barrier per chunk, vmcnt never
// drained to 0 in the loop (T4). NOTE: no 2nd __launch_bounds__ arg (R4-R6:
// it halves the VGPR pool and forces spill).
__global__ __launch_bounds__(512) void fused_attn(
    const float* __restrict__ charv, const float* __restrict__ wordv,
    const unsigned short* __restrict__ wt,
    const float* __restrict__ bk, const float* __restrict__ bq,
    const float* __restrict__ bv, float* __restrict__ out) {
  extern __shared__ char lds[];
  float* biasL = (float*)(lds + 3 * CH_BYTES);  // [1536]
  float* sS    = biasL + 1536;                  // [2 cg][64 w][4]; reused as sAt
  float* sAt   = sS;                            // aliased (safe: per-thread R->W)

  const int tid  = threadIdx.x;
  const int wid  = tid >> 6;
  const int lane = tid & 63;
  const int lrow = lane & 15;
  const int kgrp = lane >> 4;
  const int rg   = wid >> 1;   // 0..3 : rows rg*32 .. +32
  const int cg   = wid & 1;    // 0..1 : 16-col half within a 32-col group

  auto stage = [&](int t) {
    const char* src = (const char*)wt + (long)t * CH_BYTES + wid * (SEGW * 1024) + lane * 16;
    char* dst = lds + (t % 3) * CH_BYTES + wid * (SEGW * 1024);
#pragma unroll
    for (int j = 0; j < SEGW; ++j)
      gload_lds16(src + j * 1024, dst + j * 1024);
  };

  // ---- prologue: biases -> LDS, X -> regs, then stage chunks 0,1
  for (int i = tid; i < 1536; i += 512) {
    float v = (i < 512) ? bq[i] : ((i < 1024) ? bk[i - 512] : bv[i - 1024]);
    biasL[i] = v;
  }
  bf16x8 a[2][KSTEPS];
#pragma unroll
  for (int rt = 0; rt < 2; ++rt) {
    int row = blockIdx.x * ROWS + rg * 32 + rt * 16 + lrow;
    const float* rp = ((row & 1) ? charv : wordv) + (row >> 1) * D;
#pragma unroll
    for (int ks = 0; ks < KSTEPS; ++ks) {
      int k0 = ks * 32 + kgrp * 8;
      float4 lo = {0.f, 0.f, 0.f, 0.f}, hi = {0.f, 0.f, 0.f, 0.f};
      if (k0 + 8 <= D) {
        lo = *(const float4*)(rp + k0);
        hi = *(const float4*)(rp + k0 + 4);
      } else if (k0 < D) {
        lo = *(const float4*)(rp + k0);
      }
      bf16x8 v;
      v[0] = (short)f2bf(lo.x); v[1] = (short)f2bf(lo.y);
      v[2] = (short)f2bf(lo.z); v[3] = (short)f2bf(lo.w);
      v[4] = (short)f2bf(hi.x); v[5] = (short)f2bf(hi.y);
      v[6] = (short)f2bf(hi.z); v[7] = (short)f2bf(hi.w);
      a[rt][ks] = v;
    }
  }
  stage(0);
  stage(1);

  float p[2][8];
#pragma unroll
  for (int rt = 0; rt < 2; ++rt)
#pragma unroll
    for (int t = 0; t < 8; ++t) p[rt][t] = 0.f;

  const int fq = (cg * 16 + lrow) * 64 + kgrp * 16;  // Q-frag byte off in ks-block
  // K-frag = fq + 2048 (cols 32..63)

  // ---- Phase A: 16 [Q_g|K_g] chunks, 1 barrier each, counted vmcnt
  for (int t = 0; t < 16; ++t) {
    asm volatile("s_waitcnt vmcnt(5)" ::: "memory");   // chunk t staged; t+1 in flight
    asm volatile("s_waitcnt lgkmcnt(0)" ::: "memory"); // my LDS reads of t-1 done
    __builtin_amdgcn_s_barrier();
    stage(t + 2);                                      // overwrites buf of t-1 (all done)
    const char* buf = lds + (t % 3) * CH_BYTES;
    float bqv = biasL[t * 32 + cg * 16 + lrow];
    float bkv = biasL[512 + t * 32 + cg * 16 + lrow];
    f32x4 accQ[2], accK[2];
    accQ[0] = (f32x4){bqv, bqv, bqv, bqv}; accQ[1] = accQ[0];
    accK[0] = (f32x4){bkv, bkv, bkv, bkv}; accK[1] = accK[0];
#pragma unroll
    for (int ks = 0; ks < KSTEPS; ++ks) {
      bf16x8 bquf = *(const bf16x8*)(buf + ks * 4096 + fq);
      bf16x8 bkuf = *(const bf16x8*)(buf + ks * 4096 + fq + 2048);
      accQ[0] = __builtin_amdgcn_mfma_f32_16x16x32_bf16(a[0][ks], bquf, accQ[0], 0, 0, 0);
      accQ[1] = __builtin_amdgcn_mfma_f32_16x16x32_bf16(a[1][ks], bquf, accQ[1], 0, 0, 0);
      accK[0] = __builtin_amdgcn_mfma_f32_16x16x32_bf16(a[0][ks], bkuf, accK[0], 0, 0, 0);
      accK[1] = __builtin_amdgcn_mfma_f32_16x16x32_bf16(a[1][ks], bkuf, accK[1], 0, 0, 0);
    }
    // lane-local score partials (same lane holds Q and K for same (word,col))
#pragma unroll
    for (int rt = 0; rt < 2; ++rt)
#pragma unroll
      for (int wl = 0; wl < 2; ++wl)
#pragma unroll
        for (int i = 0; i < 2; ++i)
#pragma unroll
          for (int j = 0; j < 2; ++j)
            p[rt][wl * 4 + i * 2 + j] += accQ[rt][wl * 2 + i] * accK[rt][wl * 2 + j];
  }

  // ---- scores: reduce over 16 col-lanes, combine cg halves, softmax
#pragma unroll
  for (int rt = 0; rt < 2; ++rt)
#pragma unroll
    for (int t = 0; t < 8; ++t) {
      float v = p[rt][t];
      v += __shfl_xor(v, 1);
      v += __shfl_xor(v, 2);
      v += __shfl_xor(v, 4);
      v += __shfl_xor(v, 8);
      p[rt][t] = v;
    }
  if (lrow == 0) {
#pragma unroll
    for (int rt = 0; rt < 2; ++rt)
#pragma unroll
      for (int t = 0; t < 8; ++t) {
        int w = rg * 16 + rt * 8 + kgrp * 2 + (t >> 2);
        sS[cg * 256 + w * 4 + (t & 3)] = p[rt][t];
      }
  }
  asm volatile("s_waitcnt lgkmcnt(0)" ::: "memory");
  __builtin_amdgcn_s_barrier();
  if (tid < 64) {
    const float sc = 0.044194173824159216f;  // 1/sqrt(512)
    float s[4];
#pragma unroll
    for (int t = 0; t < 4; ++t) s[t] = (sS[tid * 4 + t] + sS[256 + tid * 4 + t]) * sc;
#pragma unroll
    for (int i = 0; i < 2; ++i) {
      float m  = fmaxf(s[i * 2], s[i * 2 + 1]);
      float e0 = expf(s[i * 2] - m), e1 = expf(s[i * 2 + 1] - m);
      float inv = 1.0f / (e0 + e1);
      sAt[tid * 4 + i * 2]     = e0 * inv;
      sAt[tid * 4 + i * 2 + 1] = e1 * inv;
    }
  }
  asm volatile("s_waitcnt lgkmcnt(0)" ::: "memory");
  __builtin_amdgcn_s_barrier();

  float at0[2][4], at1[2][4];
#pragma unroll
  for (int rt = 0; rt < 2; ++rt) {
    int wA = rg * 16 + rt * 8 + kgrp * 2;
#pragma unroll
    for (int t = 0; t < 4; ++t) {
      at0[rt][t] = sAt[wA * 4 + t];
      at1[rt][t] = sAt[(wA + 1) * 4 + t];
    }
  }

  // ---- Phase B: 8 V chunks; vmcnt(21) lets the 16 stores/iter stay in flight
  for (int t = 16; t < NCH; ++t) {
    if (t == 16) asm volatile("s_waitcnt vmcnt(5)" ::: "memory");
    else         asm volatile("s_waitcnt vmcnt(21)" ::: "memory");
    asm volatile("s_waitcnt lgkmcnt(0)" ::: "memory");
    __builtin_amdgcn_s_barrier();
    if (t + 2 < NCH) stage(t + 2);
    const char* buf = lds + (t % 3) * CH_BYTES;
    const int g = t - 16;
    f32x4 accV[2][2];
#pragma unroll
    for (int ct = 0; ct < 2; ++ct) {
      float b = biasL[1024 + g * 64 + cg * 32 + ct * 16 + lrow];
      accV[0][ct] = (f32x4){b, b, b, b};
      accV[1][ct] = accV[0][ct];
    }
    const int fv = (cg * 32 + lrow) * 64 + kgrp * 16;
#pragma unroll
    for (int ks = 0; ks < KSTEPS; ++ks) {
      bf16x8 b0 = *(const bf16x8*)(buf + ks * 4096 + fv);
      bf16x8 b1 = *(const bf16x8*)(buf + ks * 4096 + fv + 1024);
      accV[0][0] = __builtin_amdgcn_mfma_f32_16x16x32_bf16(a[0][ks], b0, accV[0][0], 0, 0, 0);
      accV[1][0] = __builtin_amdgcn_mfma_f32_16x16x32_bf16(a[1][ks], b0, accV[1][0], 0, 0, 0);
      accV[0][1] = __builtin_amdgcn_mfma_f32_16x16x32_bf16(a[0][ks], b1, accV[0][1], 0, 0, 0);
      accV[1][1] = __builtin_amdgcn_mfma_f32_16x16x32_bf16(a[1][ks], b1, accV[1][1], 0, 0, 0);
    }
#pragma unroll
    for (int rt = 0; rt < 2; ++rt) {
      int gA = blockIdx.x * WPB + rg * 16 + rt * 8 + kgrp * 2;
#pragma unroll
      for (int ct = 0; ct < 2; ++ct) {
        int h = g * 64 + cg * 32 + ct * 16 + lrow;
        float* o = out + gA * 1024 + h;
        o[0]    = at0[rt][0] * accV[rt][ct][0] + at0[rt][1] * accV[rt][ct][1];
        o[512]  = at0[rt][2] * accV[rt][ct][0] + at0[rt][3] * accV[rt][ct][1];
        o[1024] = at1[rt][0] * accV[rt][ct][2] + at1[rt][1] * accV[rt][ct][3];
        o[1536] = at1[rt][2] * accV[rt][ct][2] + at1[rt][3] * accV[rt][ct][3];
      }
    }
  }
}

extern "C" void kernel_launch(void* const* d_in, const int* in_sizes, int n_in,
                              void* d_out, int out_size, void* d_ws, size_t ws_size,
                              hipStream_t stream) {
  const float* charv = (const float*)d_in[0];
  const float* wordv = (const float*)d_in[1];
  const float* Wk = (const float*)d_in[2];
  const float* bk = (const float*)d_in[3];
  const float* Wq = (const float*)d_in[4];
  const float* bq = (const float*)d_in[5];
  const float* Wv = (const float*)d_in[6];
  const float* bv = (const float*)d_in[7];
  float* out = (float*)d_out;
  unsigned short* wt = (unsigned short*)d_ws;  // 24*20480*2 = 983,040 B

  prep_weights<<<NCH * CH_ELEMS / 512, 512, 0, stream>>>(Wq, Wk, Wv, wt);

  const int lds_bytes = 3 * CH_BYTES + 1536 * 4 + 512 * 4;  // 131,072 = 128 KiB exactly
  fused_attn<<<65536 / ROWS, 512, lds_bytes, stream>>>(charv, wordv, wt, bk, bq, bv, out);
}

// Round 10
// 87.473 us; speedup vs baseline: 2.5719x; 1.1277x over previous
//
#include <hip/hip_runtime.h>

#define D 300
#define HDIM 512
#define ROWS 256          // X rows per block (grid 256 = 1 block/CU)
#define WPB 128           // words per block
#define NKS 20            // K-steps of 16
#define NCH 24            // 16 [Q|K] chunks + 8 V chunks, 64 cols each
#define CH_BYTES 40960
#define CH_ELEMS 20480
#define REG_BYTES 20480   // 32-col region: 10240 elems
#define SEGW 5            // 1KB staging segments per wave per chunk

typedef __attribute__((ext_vector_type(16))) float f32x16;
typedef __attribute__((ext_vector_type(4))) float f32x4;
typedef __attribute__((ext_vector_type(8))) short bf16x8;

__device__ inline unsigned short f2bf(float f) {
  unsigned int u = __float_as_uint(f);
  unsigned int r = (u + 0x7fffu + ((u >> 16) & 1u)) >> 16;
  return (unsigned short)r;
}

__device__ inline void gload_lds16(const void* g, void* l) {
  __builtin_amdgcn_global_load_lds(
      (const __attribute__((address_space(1))) unsigned int*)g,
      (__attribute__((address_space(3))) unsigned int*)l, 16, 0, 0);
}

// Chunk layout: chunk = [regionA 10240 elems][regionB 10240 elems]; region =
// [ks20][kh2][col32][e8] so lane l reads its 32x32x16 B-fragment at byte
// (l>>5)*512 + (l&31)*16 -> consecutive lanes read consecutive 16B = NO bank
// conflicts (R9's [col][kg] order was stride-64B = the persistent 7.9M).
// c<16: regionA = Wq cols c*32.., regionB = Wk cols c*32..
// c>=16: regionA/B = Wv cols (c-16)*64 .. +32 .. +64.  k>=300 zero-padded.
__global__ __launch_bounds__(512) void prep_weights(
    const float* __restrict__ Wq, const float* __restrict__ Wk,
    const float* __restrict__ Wv, unsigned short* __restrict__ wt) {
  int idx = blockIdx.x * 512 + threadIdx.x;
  if (idx >= NCH * CH_ELEMS) return;
  int c = idx / CH_ELEMS, r = idx - c * CH_ELEMS;
  int reg = r / 10240, r2 = r - reg * 10240;
  int ks = r2 >> 9, r3 = r2 & 511;
  int kh = r3 >> 8, r4 = r3 & 255;
  int col = r4 >> 3, e = r4 & 7;
  int k = ks * 16 + kh * 8 + e;
  const float* M; int gcol;
  if (c < 16) { M = reg ? Wk : Wq; gcol = c * 32 + col; }
  else        { M = Wv; gcol = (c - 16) * 64 + reg * 32 + col; }
  float v = (k < D) ? M[k * HDIM + gcol] : 0.0f;
  wt[idx] = f2bf(v);
}

// 32x32x16 MFMA, triple-buffered counted-vmcnt pipeline (T4), 1 barrier/chunk.
// NOTE: no 2nd __launch_bounds__ arg (R4-R6: halves VGPR pool -> spill).
__global__ __launch_bounds__(512) void fused_attn(
    const float* __restrict__ charv, const float* __restrict__ wordv,
    const unsigned short* __restrict__ wt,
    const float* __restrict__ bk, const float* __restrict__ bq,
    const float* __restrict__ bv, float* __restrict__ out) {
  extern __shared__ char lds[];
  float* biasL = (float*)(lds + 3 * CH_BYTES);  // [1536]
  float* sS    = biasL + 1536;                  // [128 w][4]; reused as sAt
  float* sAt   = sS;                            // aliased (per-thread R->W, barrier-separated)

  const int tid  = threadIdx.x;
  const int wid  = tid >> 6;
  const int lane = tid & 63;
  const int lo5  = lane & 31;
  const int hi   = lane >> 5;

  auto stage = [&](int t) {
    const char* src = (const char*)wt + (long)t * CH_BYTES + wid * (SEGW * 1024) + lane * 16;
    char* dst = lds + (t % 3) * CH_BYTES + wid * (SEGW * 1024);
#pragma unroll
    for (int j = 0; j < SEGW; ++j)
      gload_lds16(src + j * 1024, dst + j * 1024);
  };

  // ---- prologue: biases -> LDS, X -> regs (32x32x16 A-frags), stage 0,1
  for (int i = tid; i < 1536; i += 512) {
    float v = (i < 512) ? bq[i] : ((i < 1024) ? bk[i - 512] : bv[i - 1024]);
    biasL[i] = v;
  }
  // A-frag: lane holds A[row=lo5][k=ks*16+hi*8+e]; wave rows wid*32..+32
  bf16x8 a[NKS];
  {
    int row = blockIdx.x * ROWS + wid * 32 + lo5;
    const float* rp = ((row & 1) ? charv : wordv) + (row >> 1) * D;
#pragma unroll
    for (int ks = 0; ks < NKS; ++ks) {
      int k0 = ks * 16 + hi * 8;
      float4 lo = {0.f, 0.f, 0.f, 0.f}, hif = {0.f, 0.f, 0.f, 0.f};
      if (k0 + 8 <= D) {
        lo  = *(const float4*)(rp + k0);
        hif = *(const float4*)(rp + k0 + 4);
      } else if (k0 < D) {
        lo  = *(const float4*)(rp + k0);
      }
      bf16x8 v;
      v[0] = (short)f2bf(lo.x);  v[1] = (short)f2bf(lo.y);
      v[2] = (short)f2bf(lo.z);  v[3] = (short)f2bf(lo.w);
      v[4] = (short)f2bf(hif.x); v[5] = (short)f2bf(hif.y);
      v[6] = (short)f2bf(hif.z); v[7] = (short)f2bf(hif.w);
      a[ks] = v;
    }
  }
  stage(0);
  stage(1);

  // score partials: p[tt*4 + i*2 + j] for word-pair slot tt (8 words/lane)
  float p[32];
#pragma unroll
  for (int t = 0; t < 32; ++t) p[t] = 0.f;

  // ---- Phase A: 16 [Q|K] chunks
  for (int t = 0; t < 16; ++t) {
    asm volatile("s_waitcnt vmcnt(5)" ::: "memory");    // stage(t) landed; t+1 in flight
    asm volatile("s_waitcnt lgkmcnt(0)" ::: "memory");
    __builtin_amdgcn_s_barrier();
    stage(t + 2);
    const char* base = lds + (t % 3) * CH_BYTES + hi * 512 + lo5 * 16;
    float bqv = biasL[t * 32 + lo5];
    float bkv = biasL[512 + t * 32 + lo5];
    f32x16 accQ, accK;
#pragma unroll
    for (int r = 0; r < 16; ++r) { accQ[r] = bqv; accK[r] = bkv; }
#pragma unroll
    for (int ks = 0; ks < NKS; ++ks) {
      bf16x8 qb = *(const bf16x8*)(base + ks * 1024);
      bf16x8 kb = *(const bf16x8*)(base + REG_BYTES + ks * 1024);
      accQ = __builtin_amdgcn_mfma_f32_32x32x16_bf16(a[ks], qb, accQ, 0, 0, 0);
      accK = __builtin_amdgcn_mfma_f32_32x32x16_bf16(a[ks], kb, accK, 0, 0, 0);
    }
    // lane-local: regs (2tt,2tt+1) = rows (2w,2w+1) of word w = (tt>>1)*4+(tt&1)+hi*2
#pragma unroll
    for (int tt = 0; tt < 8; ++tt)
#pragma unroll
      for (int i = 0; i < 2; ++i)
#pragma unroll
        for (int j = 0; j < 2; ++j)
          p[tt * 4 + i * 2 + j] += accQ[2 * tt + i] * accK[2 * tt + j];
  }

  // ---- reduce over 32 col-lanes (masks keep hi fixed), write scores
#pragma unroll
  for (int t = 0; t < 32; ++t) {
    float v = p[t];
    v += __shfl_xor(v, 1);
    v += __shfl_xor(v, 2);
    v += __shfl_xor(v, 4);
    v += __shfl_xor(v, 8);
    v += __shfl_xor(v, 16);
    p[t] = v;
  }
  if (lo5 == 0) {
#pragma unroll
    for (int tt = 0; tt < 8; ++tt) {
      int w = wid * 16 + (tt >> 1) * 4 + (tt & 1) + hi * 2;
#pragma unroll
      for (int q = 0; q < 4; ++q) sS[w * 4 + q] = p[tt * 4 + q];
    }
  }
  asm volatile("s_waitcnt lgkmcnt(0)" ::: "memory");
  __builtin_amdgcn_s_barrier();
  if (tid < 128) {
    const float sc = 0.044194173824159216f;  // 1/sqrt(512)
    float s[4];
#pragma unroll
    for (int t = 0; t < 4; ++t) s[t] = sS[tid * 4 + t] * sc;
#pragma unroll
    for (int i = 0; i < 2; ++i) {
      float m  = fmaxf(s[i * 2], s[i * 2 + 1]);
      float e0 = expf(s[i * 2] - m), e1 = expf(s[i * 2 + 1] - m);
      float inv = 1.0f / (e0 + e1);
      sAt[tid * 4 + i * 2]     = e0 * inv;
      sAt[tid * 4 + i * 2 + 1] = e1 * inv;
    }
  }
  asm volatile("s_waitcnt lgkmcnt(0)" ::: "memory");
  __builtin_amdgcn_s_barrier();

  // attention weights for this lane's 8 words
  f32x4 at[8];
#pragma unroll
  for (int tt = 0; tt < 8; ++tt) {
    int w = wid * 16 + (tt >> 1) * 4 + (tt & 1) + hi * 2;
    at[tt] = *(const f32x4*)(sAt + w * 4);
  }

  // ---- Phase B: 8 V chunks + attention combine
  for (int t = 16; t < NCH; ++t) {
    if (t == 16) asm volatile("s_waitcnt vmcnt(5)" ::: "memory");
    else         asm volatile("s_waitcnt vmcnt(37)" ::: "memory");  // 5 stage + 32 stores newer
    asm volatile("s_waitcnt lgkmcnt(0)" ::: "memory");
    __builtin_amdgcn_s_barrier();
    if (t + 2 < NCH) stage(t + 2);
    const char* base = lds + (t % 3) * CH_BYTES + hi * 512 + lo5 * 16;
    const int g = t - 16;
#pragma unroll
    for (int ct = 0; ct < 2; ++ct) {
      float bvv = biasL[1024 + g * 64 + ct * 32 + lo5];
      f32x16 accV;
#pragma unroll
      for (int r = 0; r < 16; ++r) accV[r] = bvv;
#pragma unroll
      for (int ks = 0; ks < NKS; ++ks) {
        bf16x8 vb = *(const bf16x8*)(base + ct * REG_BYTES + ks * 1024);
        accV = __builtin_amdgcn_mfma_f32_32x32x16_bf16(a[ks], vb, accV, 0, 0, 0);
      }
      int h = g * 64 + ct * 32 + lo5;
#pragma unroll
      for (int tt = 0; tt < 8; ++tt) {
        int w = wid * 16 + (tt >> 1) * 4 + (tt & 1) + hi * 2;
        long gw = (long)(blockIdx.x * WPB + w);
        float v0 = accV[2 * tt], v1 = accV[2 * tt + 1];
        out[gw * 1024 + h]       = at[tt][0] * v0 + at[tt][1] * v1;
        out[gw * 1024 + 512 + h] = at[tt][2] * v0 + at[tt][3] * v1;
      }
    }
  }
}

extern "C" void kernel_launch(void* const* d_in, const int* in_sizes, int n_in,
                              void* d_out, int out_size, void* d_ws, size_t ws_size,
                              hipStream_t stream) {
  const float* charv = (const float*)d_in[0];
  const float* wordv = (const float*)d_in[1];
  const float* Wk = (const float*)d_in[2];
  const float* bk = (const float*)d_in[3];
  const float* Wq = (const float*)d_in[4];
  const float* bq = (const float*)d_in[5];
  const float* Wv = (const float*)d_in[6];
  const float* bv = (const float*)d_in[7];
  float* out = (float*)d_out;
  unsigned short* wt = (unsigned short*)d_ws;  // 24*20480*2 = 983,040 B

  prep_weights<<<(NCH * CH_ELEMS + 511) / 512, 512, 0, stream>>>(Wq, Wk, Wv, wt);

  const int lds_bytes = 3 * CH_BYTES + 1536 * 4 + 512 * 4;  // 131,072 = 128 KiB
  fused_attn<<<65536 / ROWS, 512, lds_bytes, stream>>>(charv, wordv, wt, bk, bq, bv, out);
}